// Round 1
// baseline (439.730 us; speedup 1.0000x reference)
//
#include <hip/hip_runtime.h>

#define W_ 512
#define H_ 512
#define HW (512 * 512)
#define P_ 20
#define B_ 8
#define TL_ 29
#define IL_ 9

// One advect step: reads carry (either frames[:,IL-1] or previous evo_result*128),
// computes bilinear + nearest gathers, writes evo_result (nxt/128) and evo_motion.
__global__ __launch_bounds__(256) void step_kernel(
    const float* __restrict__ prev_base,   // carry source, per-batch stride prev_stride
    long prev_stride,                      // elements between batches in prev
    float prev_scale,                      // 1.0 for frames, 128.0 for evo_result readback
    const float* __restrict__ motion,      // (B, 2P, H, W)
    const float* __restrict__ intensity,   // (B, P, H, W)
    float* __restrict__ evo_result,        // (B, P, H, W)
    float* __restrict__ evo_motion,        // (B, P, H, W)
    int p)
{
    int idx = blockIdx.x * blockDim.x + threadIdx.x;
    if (idx >= B_ * HW) return;
    int b   = idx >> 18;          // / HW
    int rem = idx & (HW - 1);
    int y   = rem >> 9;           // / W
    int x   = rem & (W_ - 1);

    const float* prev = prev_base + (long)b * prev_stride;

    float flow0 = motion[((long)b * (2 * P_) + 2 * p    ) * HW + rem];
    float flow1 = motion[((long)b * (2 * P_) + 2 * p + 1) * HW + rem];
    float inten = intensity[((long)b * P_ + p) * HW + rem];

    float cx = fminf(fmaxf((float)x + flow0, 0.0f), 511.0f);
    float cy = fminf(fmaxf((float)y + flow1, 0.0f), 511.0f);

    // bilinear
    float x0f = floorf(cx), y0f = floorf(cy);
    float wx = cx - x0f, wy = cy - y0f;
    int x0 = (int)x0f, y0 = (int)y0f;
    int x1 = min(x0 + 1, W_ - 1), y1 = min(y0 + 1, H_ - 1);

    float v00 = prev[y0 * W_ + x0];
    float v01 = prev[y0 * W_ + x1];
    float v10 = prev[y1 * W_ + x0];
    float v11 = prev[y1 * W_ + x1];
    float bili = prev_scale *
        ((1.0f - wy) * ((1.0f - wx) * v00 + wx * v01) +
                 wy  * ((1.0f - wx) * v10 + wx * v11));

    // nearest (round half-to-even, same as jnp.round)
    int xi = (int)rintf(cx);
    int yi = (int)rintf(cy);
    float nxt = prev_scale * prev[yi * W_ + xi] + inten;

    long o = ((long)b * P_ + p) * HW + rem;
    evo_result[o] = nxt * (1.0f / 128.0f);
    evo_motion[o] = bili;
}

extern "C" void kernel_launch(void* const* d_in, const int* in_sizes, int n_in,
                              void* d_out, int out_size, void* d_ws, size_t ws_size,
                              hipStream_t stream)
{
    const float* frames    = (const float*)d_in[0];  // (B, TL, H, W, 1)
    const float* motion    = (const float*)d_in[1];  // (B, 2P, H, W)
    const float* intensity = (const float*)d_in[2];  // (B, P, H, W)

    float* out        = (float*)d_out;
    float* evo_result = out;                          // B*P*HW
    float* evo_motion = out + (long)B_ * P_ * HW;     // B*P*HW
    float* motion_out = out + 2L * B_ * P_ * HW;      // B*2P*HW

    // motion_ output is a pure reshape -> D2D copy (independent; issue first)
    hipMemcpyAsync(motion_out, motion, (size_t)B_ * 2 * P_ * HW * sizeof(float),
                   hipMemcpyDeviceToDevice, stream);

    const int threads = 256;
    const int blocks  = (B_ * HW + threads - 1) / threads;

    // step 0: carry = frames[:, IL-1, :, :, 0]
    step_kernel<<<blocks, threads, 0, stream>>>(
        frames + (long)(IL_ - 1) * HW, (long)TL_ * HW, 1.0f,
        motion, intensity, evo_result, evo_motion, 0);

    // steps 1..P-1: carry = evo_result[:, p-1] * 128 (exact)
    for (int p = 1; p < P_; ++p) {
        step_kernel<<<blocks, threads, 0, stream>>>(
            evo_result + (long)(p - 1) * HW, (long)P_ * HW, 128.0f,
            motion, intensity, evo_result, evo_motion, p);
    }
}